// Round 4
// baseline (134.692 us; speedup 1.0000x reference)
//
#include <hip/hip_runtime.h>

// N=32, C=96, H=W=56. HW=3136, NP=100352.
// d_out = [ out (9,633,792 f32) | fmap (9,633,792 f32) ]
//
// ws layout (float index):
//   [    0, 9216) w1t[(g*96+ci)*48 + o] = w1[(g*48+o)*96 + ci]
//   [ 9216, 9408) s1[192]
//   [ 9408, 9600) b1[192]

#define WS_W1T 0
#define WS_S1  9216
#define WS_B1  9408

#define HW 3136
#define CC 96
#define NB 32

__global__ __launch_bounds__(256) void precompute_k(
    const float* __restrict__ g1, const float* __restrict__ be1,
    const float* __restrict__ m1, const float* __restrict__ v1,
    const float* __restrict__ w1, float* __restrict__ ws) {
  const int tid = threadIdx.x;
  for (int i = tid; i < 9216; i += 256) {
    int gci = i / 48, o = i - gci * 48;
    int g = gci / 96, ci = gci - g * 96;
    ws[WS_W1T + i] = w1[(g * 48 + o) * 96 + ci];
  }
  if (tid < 192) {
    float s = g1[tid] / sqrtf(v1[tid] + 1e-5f);
    ws[WS_S1 + tid] = s;
    ws[WS_B1 + tid] = be1[tid] - m1[tid] * s;
  }
}

// ---------------------------------------------------------------------------
// K1: fmap = conv1x1_g2( bnrelu1( concat(x0, f1, x1, f0) ), w1 )
// grid = 1568 = 784 px-tiles x 2 groups. Block 256 = 4 waves:
//   wave = (px-sub 0/1, out-half 0/1). Thread: 1 px x 24 outs = 24 accs.
// Weights (18KB, pre-transposed in ws) staged in LDS; uniform ds_read
// broadcasts leave the vmem pipe entirely to activation streams.
// ---------------------------------------------------------------------------
__global__ __launch_bounds__(256) void k1_conv1(
    const float* __restrict__ x, const float* __restrict__ prev,
    const float* __restrict__ ws, float* __restrict__ fmap) {
  __shared__ float lw[96 * 48];   // lw[ci*48+o] for this block's group
  __shared__ float ls[96], lb[96];

  const int tid = threadIdx.x;
  const int g = blockIdx.x & 1;
  const int tile = blockIdx.x >> 1;

  {
    const float* src = ws + WS_W1T + g * (96 * 48);
    for (int t = tid; t < 96 * 48; t += 256) lw[t] = src[t];
    if (tid < 96) {
      ls[tid] = ws[WS_S1 + g * 96 + tid];
      lb[tid] = ws[WS_B1 + g * 96 + tid];
    }
  }
  __syncthreads();

  const int lane = tid & 63;
  const int wv = tid >> 6;
  const int h = wv & 1;        // out-half: outs [h*24, h*24+24)
  const int psub = wv >> 1;    // px sub-tile

  const int px = tile * 128 + psub * 64 + lane;
  const int n = px / HW, p = px - n * HW;
  const int base = n * CC * HW + p;

  // ci in [0,48): x (+48*HW if g==1); ci in [48,96): prev (-48*HW if g==1),
  // both indexed as ptr[ci*HW].
  const float* PA = x + base + (g ? 48 * HW : 0);
  const float* PB = prev + base + (g ? -48 * HW : 0);

  float acc[24];
#pragma unroll
  for (int o = 0; o < 24; ++o) acc[o] = 0.f;

  float buf[4];
#pragma unroll
  for (int k = 0; k < 4; ++k) buf[k] = PA[k * HW];

#pragma unroll 4
  for (int ci = 0; ci < 96; ++ci) {
    const float c0 = buf[ci & 3];
    const int nx = ci + 4;
    if (nx < 96) {
      const float* q = (nx < 48) ? PA : PB;
      buf[ci & 3] = q[nx * HW];
    }
    const float a = fmaxf(fmaf(c0, ls[ci], lb[ci]), 0.f);
    const float* wr = &lw[ci * 48 + h * 24];
#pragma unroll
    for (int o = 0; o < 24; ++o) acc[o] = fmaf(wr[o], a, acc[o]);
  }

  float* F = fmap + base + (g * 48 + h * 24) * HW;
#pragma unroll
  for (int o = 0; o < 24; ++o) F[o * HW] = acc[o];
}

// ---------------------------------------------------------------------------
// K2: out = conv1x1_g3( active_shift( bnrelu2(fmap) ), w2 ) + x
// (unchanged — measured ~9 us with precompute)
// ---------------------------------------------------------------------------
__global__ __launch_bounds__(192) void k2_shift_conv2(
    const float* __restrict__ x, const float* __restrict__ fmap,
    const float* __restrict__ g2, const float* __restrict__ be2,
    const float* __restrict__ m2, const float* __restrict__ v2,
    const float* __restrict__ w2, const float* __restrict__ shift,
    float* __restrict__ out) {
  __shared__ float lw[96 * 32];   // lw[c*32+o] = w2[((c>>5)*32+o)*32 + (c&31)]
  __shared__ float prm[96][8];

  const int tid = threadIdx.x;
  for (int t = tid; t < 96 * 32; t += 192) {
    int c = t >> 5, o = t & 31;
    lw[t] = w2[((c >> 5) * 32 + o) * 32 + (c & 31)];
  }
  if (tid < 96) {
    int c = tid;
    float s = g2[c] / sqrtf(v2[c] + 1e-5f);
    float b = be2[c] - m2[c] * s;
    float dy = shift[2 * c], dx = shift[2 * c + 1];
    float fy = floorf(dy), fx = floorf(dx);
    float wy = dy - fy, wx = dx - fx;
    prm[c][0] = s;
    prm[c][1] = b;
    prm[c][2] = (1.f - wy) * (1.f - wx);
    prm[c][3] = (1.f - wy) * wx;
    prm[c][4] = wy * (1.f - wx);
    prm[c][5] = wy * wx;
    prm[c][6] = __int_as_float((int)fy);
    prm[c][7] = __int_as_float((int)fx);
  }
  __syncthreads();

  const int G = tid >> 6;          // group 0..2
  const int lane = tid & 63;
  const int px0 = blockIdx.x * 128 + lane;
  const int px1 = px0 + 64;
  const int n0 = px0 / HW, p0 = px0 - n0 * HW;
  const int n1 = px1 / HW, p1 = px1 - n1 * HW;
  const int y0 = p0 / 56, x0c = p0 - y0 * 56;
  const int y1 = p1 / 56, x1c = p1 - y1 * 56;

  const float* fb0 = fmap + (n0 * CC + G * 32) * HW;
  const float* fb1 = fmap + (n1 * CC + G * 32) * HW;

  float acc0[32], acc1[32];
#pragma unroll
  for (int o = 0; o < 32; ++o) { acc0[o] = 0.f; acc1[o] = 0.f; }

  for (int ci = 0; ci < 32; ++ci) {
    const int c = G * 32 + ci;
    const float s = prm[c][0], b = prm[c][1];
    const float w00 = prm[c][2], w01 = prm[c][3];
    const float w10 = prm[c][4], w11 = prm[c][5];
    const int ay = __float_as_int(prm[c][6]);
    const int ax = __float_as_int(prm[c][7]);
    const int off = ay * 56 + ax;
    const float* fc0 = fb0 + ci * HW;
    const float* fc1 = fb1 + ci * HW;

    float h0, h1;
    {
      const int yq = y0 + ay, xq = x0c + ax;
      const int t = p0 + off;
      float f00 = fc0[min(max(t, 0), HW - 1)];
      float f01 = fc0[min(max(t + 1, 0), HW - 1)];
      float f10 = fc0[min(max(t + 56, 0), HW - 1)];
      float f11 = fc0[min(max(t + 57, 0), HW - 1)];
      float q00 = fmaxf(fmaf(f00, s, b), 0.f);
      float q01 = fmaxf(fmaf(f01, s, b), 0.f);
      float q10 = fmaxf(fmaf(f10, s, b), 0.f);
      float q11 = fmaxf(fmaf(f11, s, b), 0.f);
      const bool vy0 = yq >= 0, vy1 = yq <= 54;
      const bool vx0 = xq >= 0, vx1 = xq <= 54;
      h0 = ((vy0 && vx0) ? w00 : 0.f) * q00;
      h0 = fmaf(((vy0 && vx1) ? w01 : 0.f), q01, h0);
      h0 = fmaf(((vy1 && vx0) ? w10 : 0.f), q10, h0);
      h0 = fmaf(((vy1 && vx1) ? w11 : 0.f), q11, h0);
    }
    {
      const int yq = y1 + ay, xq = x1c + ax;
      const int t = p1 + off;
      float f00 = fc1[min(max(t, 0), HW - 1)];
      float f01 = fc1[min(max(t + 1, 0), HW - 1)];
      float f10 = fc1[min(max(t + 56, 0), HW - 1)];
      float f11 = fc1[min(max(t + 57, 0), HW - 1)];
      float q00 = fmaxf(fmaf(f00, s, b), 0.f);
      float q01 = fmaxf(fmaf(f01, s, b), 0.f);
      float q10 = fmaxf(fmaf(f10, s, b), 0.f);
      float q11 = fmaxf(fmaf(f11, s, b), 0.f);
      const bool vy0 = yq >= 0, vy1 = yq <= 54;
      const bool vx0 = xq >= 0, vx1 = xq <= 54;
      h1 = ((vy0 && vx0) ? w00 : 0.f) * q00;
      h1 = fmaf(((vy0 && vx1) ? w01 : 0.f), q01, h1);
      h1 = fmaf(((vy1 && vx0) ? w10 : 0.f), q10, h1);
      h1 = fmaf(((vy1 && vx1) ? w11 : 0.f), q11, h1);
    }

    const float* wr = &lw[c * 32];
#pragma unroll
    for (int o = 0; o < 32; ++o) {
      float w = wr[o];
      acc0[o] = fmaf(w, h0, acc0[o]);
      acc1[o] = fmaf(w, h1, acc1[o]);
    }
  }

  const int ob0 = (n0 * CC + G * 32) * HW + p0;
  const int ob1 = (n1 * CC + G * 32) * HW + p1;
#pragma unroll
  for (int o = 0; o < 32; ++o) {
    out[ob0 + o * HW] = acc0[o] + x[ob0 + o * HW];
    out[ob1 + o * HW] = acc1[o] + x[ob1 + o * HW];
  }
}

extern "C" void kernel_launch(void* const* d_in, const int* in_sizes, int n_in,
                              void* d_out, int out_size, void* d_ws, size_t ws_size,
                              hipStream_t stream) {
  const float* x     = (const float*)d_in[0];
  const float* prev  = (const float*)d_in[1];
  const float* g1    = (const float*)d_in[2];
  const float* be1   = (const float*)d_in[3];
  const float* m1    = (const float*)d_in[4];
  const float* v1    = (const float*)d_in[5];
  const float* g2    = (const float*)d_in[6];
  const float* be2   = (const float*)d_in[7];
  const float* m2    = (const float*)d_in[8];
  const float* v2    = (const float*)d_in[9];
  const float* w1    = (const float*)d_in[10];
  const float* w2    = (const float*)d_in[11];
  const float* shift = (const float*)d_in[12];

  float* out  = (float*)d_out;
  float* fmap = out + (size_t)NB * CC * HW;  // second output, written in place
  float* ws   = (float*)d_ws;

  precompute_k<<<1, 256, 0, stream>>>(g1, be1, m1, v1, w1, ws);
  k1_conv1<<<1568, 256, 0, stream>>>(x, prev, ws, fmap);
  k2_shift_conv2<<<784, 192, 0, stream>>>(x, fmap, g2, be2, m2, v2, w2, shift,
                                          out);
}

// Round 5
// 84.043 us; speedup vs baseline: 1.6027x; 1.6027x over previous
//
#include <hip/hip_runtime.h>
#include <hip/hip_bf16.h>
#include <string.h>

// N=32, C=96, H=W=56. HW=3136, NP=100352.
// d_out = [ out (9,633,792 f32) | fmap (9,633,792 f32) ]
//
// ws layout (bytes):
//   [0, 18432)     W1 bf16 A-frags, idx = ((g*3+m)*3+k)*64 + lane, 16 B each
//                  lane slot holds w'[o=16m+(lane&15)][ci=32k+(lane>>4)*8+j]
//                  with w' = w1 * s1 (BN scale folded), j=0..7
//   [18432,19200)  c1[192] f32: c = b/s  (act' = max(x + c, 0))
#define WSC_OFF 4608   // float index of c1

#define HW 3136
#define CC 96
#define NB 32

typedef __attribute__((ext_vector_type(8))) short short8;
typedef __attribute__((ext_vector_type(4))) float float4_;

__global__ __launch_bounds__(128) void precompute_k(
    const float* __restrict__ g1, const float* __restrict__ be1,
    const float* __restrict__ m1, const float* __restrict__ v1,
    const float* __restrict__ w1, float* __restrict__ ws) {
  const int t = blockIdx.x * 128 + threadIdx.x;  // 9*128 = 1152 threads
  if (t < 192) {
    float s = g1[t] / sqrtf(v1[t] + 1e-5f);
    float b = be1[t] - m1[t] * s;
    ws[WSC_OFF + t] = b / s;     // gamma > 0 guaranteed
  }
  // one 16-byte fragment slot per thread
  const int lane = t & 63;
  const int gmk = t >> 6;        // 0..17
  const int k = gmk % 3;
  const int gm = gmk / 3;
  const int m = gm % 3;
  const int g = gm / 3;
  const int o = 16 * m + (lane & 15);
  const int ci0 = 32 * k + (lane >> 4) * 8;
  unsigned int pk[4];
  for (int jj = 0; jj < 4; ++jj) {
    unsigned short us[2];
    for (int h = 0; h < 2; ++h) {
      int ci = ci0 + 2 * jj + h;
      float s = g1[g * 96 + ci] / sqrtf(v1[g * 96 + ci] + 1e-5f);
      float w = w1[(g * 48 + o) * 96 + ci] * s;
      __hip_bfloat16 hb = __float2bfloat16(w);
      memcpy(&us[h], &hb, 2);
    }
    pk[jj] = (unsigned int)us[0] | ((unsigned int)us[1] << 16);
  }
  uint4 val;
  val.x = pk[0]; val.y = pk[1]; val.z = pk[2]; val.w = pk[3];
  ((uint4*)ws)[t] = val;
}

// ---------------------------------------------------------------------------
// K1 (MFMA): fmap = conv1x1_g2( bnrelu1( concat ), w1 )
// grid = 1568 = 784 strips x 2 groups; block 256 = 4 waves.
// Wave: 2 tiles of 16 px, all 48 outs. Whole weight matrix register-resident
// (9 A-frags). D row=(lane>>4)*4+r, col=lane&15 (verified C/D layout).
// ---------------------------------------------------------------------------
__global__ __launch_bounds__(256) void k1_conv1(
    const float* __restrict__ x, const float* __restrict__ prev,
    const float* __restrict__ ws, float* __restrict__ fmap) {
  const int tid = threadIdx.x;
  const int lane = tid & 63;
  const int wv = tid >> 6;
  const int g = blockIdx.x & 1;
  const int strip = blockIdx.x >> 1;
  const int q = lane >> 4;       // 0..3
  const int colL = lane & 15;

  // weight fragments (bf16, scale-folded, pre-swizzled)
  short8 A[3][3];
  const short8* wf = (const short8*)ws;
#pragma unroll
  for (int m = 0; m < 3; ++m)
#pragma unroll
    for (int k = 0; k < 3; ++k)
      A[m][k] = wf[((g * 3 + m) * 3 + k) * 64 + lane];

  // per-lane act thresholds c = b/s for this lane's 24 ci
  float c_[3][8];
#pragma unroll
  for (int k = 0; k < 3; ++k) {
    const float* cp = ws + WSC_OFF + g * 96 + 32 * k + 8 * q;
#pragma unroll
    for (int j = 0; j < 8; ++j) c_[k][j] = cp[j];
  }

#pragma unroll
  for (int t = 0; t < 2; ++t) {
    const int P = strip * 128 + wv * 32 + t * 16;   // tile-aligned, 3136%16==0
    const int n = P / HW;
    const int p = P - n * HW;
    const size_t nb = (size_t)n * CC * HW;
    const int col = p + colL;

    float4_ D[3] = {{0.f, 0.f, 0.f, 0.f}, {0.f, 0.f, 0.f, 0.f},
                    {0.f, 0.f, 0.f, 0.f}};

#pragma unroll
    for (int k = 0; k < 3; ++k) {
      const int ci0 = 32 * k + 8 * q;  // octets never straddle the 48-split
      const float* src = (ci0 < 48)
          ? (x + nb + (size_t)(g * 48 + ci0) * HW + col)
          : (prev + nb + (size_t)((1 - g) * 48 + (ci0 - 48)) * HW + col);
      float a[8];
#pragma unroll
      for (int j = 0; j < 8; ++j) a[j] = src[(size_t)j * HW];
      short8 B;
#pragma unroll
      for (int j = 0; j < 8; ++j) {
        float f = fmaxf(a[j] + c_[k][j], 0.f);
        __hip_bfloat16 hb = __float2bfloat16(f);
        unsigned short us;
        memcpy(&us, &hb, 2);
        B[j] = (short)us;
      }
#pragma unroll
      for (int m = 0; m < 3; ++m)
        D[m] = __builtin_amdgcn_mfma_f32_16x16x32_bf16(A[m][k], B, D[m],
                                                       0, 0, 0);
    }

    float* fb = fmap + nb + (size_t)(g * 48) * HW + col;
#pragma unroll
    for (int m = 0; m < 3; ++m)
#pragma unroll
      for (int r = 0; r < 4; ++r)
        fb[(size_t)(16 * m + q * 4 + r) * HW] = D[m][r];
  }
}

// ---------------------------------------------------------------------------
// K2: out = conv1x1_g3( active_shift( bnrelu2(fmap) ), w2 ) + x
// (unchanged — measured ~10 us)
// ---------------------------------------------------------------------------
__global__ __launch_bounds__(192) void k2_shift_conv2(
    const float* __restrict__ x, const float* __restrict__ fmap,
    const float* __restrict__ g2, const float* __restrict__ be2,
    const float* __restrict__ m2, const float* __restrict__ v2,
    const float* __restrict__ w2, const float* __restrict__ shift,
    float* __restrict__ out) {
  __shared__ float lw[96 * 32];   // lw[c*32+o] = w2[((c>>5)*32+o)*32 + (c&31)]
  __shared__ float prm[96][8];

  const int tid = threadIdx.x;
  for (int t = tid; t < 96 * 32; t += 192) {
    int c = t >> 5, o = t & 31;
    lw[t] = w2[((c >> 5) * 32 + o) * 32 + (c & 31)];
  }
  if (tid < 96) {
    int c = tid;
    float s = g2[c] / sqrtf(v2[c] + 1e-5f);
    float b = be2[c] - m2[c] * s;
    float dy = shift[2 * c], dx = shift[2 * c + 1];
    float fy = floorf(dy), fx = floorf(dx);
    float wy = dy - fy, wx = dx - fx;
    prm[c][0] = s;
    prm[c][1] = b;
    prm[c][2] = (1.f - wy) * (1.f - wx);
    prm[c][3] = (1.f - wy) * wx;
    prm[c][4] = wy * (1.f - wx);
    prm[c][5] = wy * wx;
    prm[c][6] = __int_as_float((int)fy);
    prm[c][7] = __int_as_float((int)fx);
  }
  __syncthreads();

  const int G = tid >> 6;          // group 0..2
  const int lane = tid & 63;
  const int px0 = blockIdx.x * 128 + lane;
  const int px1 = px0 + 64;
  const int n0 = px0 / HW, p0 = px0 - n0 * HW;
  const int n1 = px1 / HW, p1 = px1 - n1 * HW;
  const int y0 = p0 / 56, x0c = p0 - y0 * 56;
  const int y1 = p1 / 56, x1c = p1 - y1 * 56;

  const float* fb0 = fmap + (n0 * CC + G * 32) * HW;
  const float* fb1 = fmap + (n1 * CC + G * 32) * HW;

  float acc0[32], acc1[32];
#pragma unroll
  for (int o = 0; o < 32; ++o) { acc0[o] = 0.f; acc1[o] = 0.f; }

  for (int ci = 0; ci < 32; ++ci) {
    const int c = G * 32 + ci;
    const float s = prm[c][0], b = prm[c][1];
    const float w00 = prm[c][2], w01 = prm[c][3];
    const float w10 = prm[c][4], w11 = prm[c][5];
    const int ay = __float_as_int(prm[c][6]);
    const int ax = __float_as_int(prm[c][7]);
    const int off = ay * 56 + ax;
    const float* fc0 = fb0 + ci * HW;
    const float* fc1 = fb1 + ci * HW;

    float h0, h1;
    {
      const int yq = y0 + ay, xq = x0c + ax;
      const int t = p0 + off;
      float f00 = fc0[min(max(t, 0), HW - 1)];
      float f01 = fc0[min(max(t + 1, 0), HW - 1)];
      float f10 = fc0[min(max(t + 56, 0), HW - 1)];
      float f11 = fc0[min(max(t + 57, 0), HW - 1)];
      float q00 = fmaxf(fmaf(f00, s, b), 0.f);
      float q01 = fmaxf(fmaf(f01, s, b), 0.f);
      float q10 = fmaxf(fmaf(f10, s, b), 0.f);
      float q11 = fmaxf(fmaf(f11, s, b), 0.f);
      const bool vy0 = yq >= 0, vy1 = yq <= 54;
      const bool vx0 = xq >= 0, vx1 = xq <= 54;
      h0 = ((vy0 && vx0) ? w00 : 0.f) * q00;
      h0 = fmaf(((vy0 && vx1) ? w01 : 0.f), q01, h0);
      h0 = fmaf(((vy1 && vx0) ? w10 : 0.f), q10, h0);
      h0 = fmaf(((vy1 && vx1) ? w11 : 0.f), q11, h0);
    }
    {
      const int yq = y1 + ay, xq = x1c + ax;
      const int t = p1 + off;
      float f00 = fc1[min(max(t, 0), HW - 1)];
      float f01 = fc1[min(max(t + 1, 0), HW - 1)];
      float f10 = fc1[min(max(t + 56, 0), HW - 1)];
      float f11 = fc1[min(max(t + 57, 0), HW - 1)];
      float q00 = fmaxf(fmaf(f00, s, b), 0.f);
      float q01 = fmaxf(fmaf(f01, s, b), 0.f);
      float q10 = fmaxf(fmaf(f10, s, b), 0.f);
      float q11 = fmaxf(fmaf(f11, s, b), 0.f);
      const bool vy0 = yq >= 0, vy1 = yq <= 54;
      const bool vx0 = xq >= 0, vx1 = xq <= 54;
      h1 = ((vy0 && vx0) ? w00 : 0.f) * q00;
      h1 = fmaf(((vy0 && vx1) ? w01 : 0.f), q01, h1);
      h1 = fmaf(((vy1 && vx0) ? w10 : 0.f), q10, h1);
      h1 = fmaf(((vy1 && vx1) ? w11 : 0.f), q11, h1);
    }

    const float* wr = &lw[c * 32];
#pragma unroll
    for (int o = 0; o < 32; ++o) {
      float w = wr[o];
      acc0[o] = fmaf(w, h0, acc0[o]);
      acc1[o] = fmaf(w, h1, acc1[o]);
    }
  }

  const int ob0 = (n0 * CC + G * 32) * HW + p0;
  const int ob1 = (n1 * CC + G * 32) * HW + p1;
#pragma unroll
  for (int o = 0; o < 32; ++o) {
    out[ob0 + o * HW] = acc0[o] + x[ob0 + o * HW];
    out[ob1 + o * HW] = acc1[o] + x[ob1 + o * HW];
  }
}

extern "C" void kernel_launch(void* const* d_in, const int* in_sizes, int n_in,
                              void* d_out, int out_size, void* d_ws, size_t ws_size,
                              hipStream_t stream) {
  const float* x     = (const float*)d_in[0];
  const float* prev  = (const float*)d_in[1];
  const float* g1    = (const float*)d_in[2];
  const float* be1   = (const float*)d_in[3];
  const float* m1    = (const float*)d_in[4];
  const float* v1    = (const float*)d_in[5];
  const float* g2    = (const float*)d_in[6];
  const float* be2   = (const float*)d_in[7];
  const float* m2    = (const float*)d_in[8];
  const float* v2    = (const float*)d_in[9];
  const float* w1    = (const float*)d_in[10];
  const float* w2    = (const float*)d_in[11];
  const float* shift = (const float*)d_in[12];

  float* out  = (float*)d_out;
  float* fmap = out + (size_t)NB * CC * HW;  // second output, written in place
  float* ws   = (float*)d_ws;

  precompute_k<<<9, 128, 0, stream>>>(g1, be1, m1, v1, w1, ws);
  k1_conv1<<<1568, 256, 0, stream>>>(x, prev, ws, fmap);
  k2_shift_conv2<<<784, 192, 0, stream>>>(x, fmap, g2, be2, m2, v2, w2, shift,
                                          out);
}